// Round 9
// baseline (140.585 us; speedup 1.0000x reference)
//
#include <hip/hip_runtime.h>
#include <math.h>

#define BB 8
#define NN 100
#define KK 20
#define DD 256
#define MM 2000                    // NN*KK anchors per batch
#define MP 2048                    // padded rows per batch
#define TINV 10.0f                 // 1/TEMP
#define LOSS_SCALE 1.953125e-7f    // ALPHA / (B_NORM*N*K*D) = 0.1/512000

typedef __bf16 bf16x8 __attribute__((ext_vector_type(8)));
typedef float floatx4 __attribute__((ext_vector_type(4)));

__device__ __forceinline__ ushort f2bf(float f) {
    unsigned int u = __float_as_uint(f);
    u += 0x7fffu + ((u >> 16) & 1u);   // round-to-nearest-even
    return (ushort)(u >> 16);
}

// ---------------- kernel 1: normalize+convert to bf16, zero-pad, write invn, zero accumulators ----------------
__global__ void norm_bf16(const float* __restrict__ x, ushort* __restrict__ xb,
                          float* __restrict__ invn_out,
                          float* __restrict__ denom_g, float* __restrict__ out) {
    // fold denom + out zero-init into this pass (no memset dispatches)
    if (blockIdx.x < 16)
        ((float4*)denom_g)[blockIdx.x * 256 + threadIdx.x] = make_float4(0.f, 0.f, 0.f, 0.f);
    if (blockIdx.x == 0 && threadIdx.x == 0) out[0] = 0.0f;

    const int rg = blockIdx.x * 4 + (threadIdx.x >> 6);   // 0..16383
    const int lane = threadIdx.x & 63;
    const int b = rg >> 11;
    const int r = rg & (MP - 1);
    ushort4 outv = make_ushort4(0, 0, 0, 0);
    if (r < MM) {   // wave-uniform branch
        const float4 v = ((const float4*)(x + ((size_t)(b * MM + r)) * DD))[lane];
        float s = v.x * v.x + v.y * v.y + v.z * v.z + v.w * v.w;
        #pragma unroll
        for (int o = 32; o >= 1; o >>= 1) s += __shfl_xor(s, o, 64);
        const float inv = 1.0f / sqrtf(s);
        if (lane == 0) invn_out[rg] = inv;
        outv.x = f2bf(v.x * inv);
        outv.y = f2bf(v.y * inv);
        outv.z = f2bf(v.z * inv);
        outv.w = f2bf(v.w * inv);
    }
    ((ushort4*)(xb + (size_t)rg * DD))[lane] = outv;
}

// ---------------- kernel 2: barrier-free all-register MFMA Gram + exp-sum epilogue ----------------
// No LDS, no __syncthreads. Each wave independently computes a 64x64 tile with
// operands loaded straight from L2-resident xb via a 2-deep kc software pipeline
// (next kc's 16 global_load_dwordx4 issued before current kc's MFMAs -> vmcnt(16)
// distance). R2 vs R7 showed per-block time is set by the 8 barrier drains, not
// staging method; this removes them entirely. XCD pin: batch = blk&7.
__global__ __launch_bounds__(256)
void cl_mfma(const ushort* __restrict__ xb, float* __restrict__ denom_g) {
    const int b = blockIdx.x & 7;            // XCD pin
    const int ti = (blockIdx.x >> 3) & 15;   // row tile (128)
    const int tj = blockIdx.x >> 7;          // col tile (128)
    const int lane = threadIdx.x & 63;
    const int w = threadIdx.x >> 6;
    const int tx = lane & 15;
    const int quad = lane >> 4;
    const int rbase = (ti << 7) + ((w >> 1) << 6);   // this wave's 64-row strip
    const int cbase = (tj << 7) + ((w & 1) << 6);    // this wave's 64-col strip
    const ushort* __restrict__ xbb = xb + (size_t)b * MP * DD;

    // lane (tx,quad) reads row (base+mt*16+tx), 16B granule at k = kc*64+ks*32+quad*8
    const ushort* __restrict__ aRow = xbb + (size_t)(rbase + tx) * DD + (quad << 3);
    const ushort* __restrict__ bRow = xbb + (size_t)(cbase + tx) * DD + (quad << 3);

    floatx4 acc[4][4];
    #pragma unroll
    for (int mt = 0; mt < 4; ++mt)
        #pragma unroll
        for (int nt = 0; nt < 4; ++nt)
            acc[mt][nt] = (floatx4){0.f, 0.f, 0.f, 0.f};

    bf16x8 af[2][4][2], bfr[2][4][2];   // [buf][tile][ks]

    // prologue: load kc=0 fragments
    #pragma unroll
    for (int mt = 0; mt < 4; ++mt)
        #pragma unroll
        for (int ks = 0; ks < 2; ++ks) {
            af[0][mt][ks]  = *(const bf16x8*)(aRow + (size_t)(mt << 4) * DD + (ks << 5));
            bfr[0][mt][ks] = *(const bf16x8*)(bRow + (size_t)(mt << 4) * DD + (ks << 5));
        }

    #pragma unroll
    for (int kc = 0; kc < 4; ++kc) {
        const int cur = kc & 1;
        const int nxt = cur ^ 1;
        if (kc < 3) {   // issue next kc's loads BEFORE current kc's MFMAs
            const int ko = (kc + 1) << 6;
            #pragma unroll
            for (int mt = 0; mt < 4; ++mt)
                #pragma unroll
                for (int ks = 0; ks < 2; ++ks) {
                    af[nxt][mt][ks]  = *(const bf16x8*)(aRow + (size_t)(mt << 4) * DD + ko + (ks << 5));
                    bfr[nxt][mt][ks] = *(const bf16x8*)(bRow + (size_t)(mt << 4) * DD + ko + (ks << 5));
                }
        }
        #pragma unroll
        for (int ks = 0; ks < 2; ++ks)
            #pragma unroll
            for (int mt = 0; mt < 4; ++mt)
                #pragma unroll
                for (int nt = 0; nt < 4; ++nt)
                    acc[mt][nt] = __builtin_amdgcn_mfma_f32_16x16x32_bf16(
                        af[cur][mt][ks], bfr[cur][nt][ks], acc[mt][nt], 0, 0, 0);
    }

    // epilogue (denom only). C/D layout: col=lane&15, row=quad*4+reg.
    int colv[4];
    bool colok[4];
    #pragma unroll
    for (int nt = 0; nt < 4; ++nt) {
        const int c = cbase + (nt << 4) + tx;
        colv[nt] = c;
        colok[nt] = c < MM;
    }

    #pragma unroll
    for (int mt = 0; mt < 4; ++mt) {
        #pragma unroll
        for (int i = 0; i < 4; ++i) {
            const int row = rbase + (mt << 4) + (quad << 2) + i;
            float de = 0.f;
            #pragma unroll
            for (int nt = 0; nt < 4; ++nt) {
                const float e = __expf(acc[mt][nt][i] * TINV);
                de += (colok[nt] && (colv[nt] != row)) ? e : 0.0f;
            }
            #pragma unroll
            for (int o = 8; o >= 1; o >>= 1)
                de += __shfl_xor(de, o, 64);
            if (tx == 0)
                atomicAdd(&denom_g[b * MP + row], de);
        }
    }
}

// ---------------- kernel 3: fused finalize ----------------
// blocks 0..799: class-group sum vectors -> analytic sum_term, atomicAdd into out
// blocks 800..862: log(denom) partial sums, atomicAdd into out
__global__ void finalize_combined(const float* __restrict__ x,
                                  const float* __restrict__ invn,
                                  const float* __restrict__ denom_g,
                                  float* __restrict__ out) {
    __shared__ float red[4];
    const int tid = threadIdx.x;
    if (blockIdx.x < 800) {
        // group (b,n): S = sum_k invn_k * x[b,n,k,:]; contribution
        // -LOSS_SCALE * TINV/(K-1) * (||S||^2 - K)
        const int g = blockIdx.x;
        const int b = g / NN;
        const int n = g - b * NN;
        const int row0 = n * KK;
        const float* __restrict__ xg = x + ((size_t)(b * MM + row0)) * DD;
        const float* __restrict__ ig = invn + b * MP + row0;
        float s = 0.0f;
        #pragma unroll
        for (int k = 0; k < KK; ++k)
            s = fmaf(ig[k], xg[(size_t)k * DD + tid], s);
        float v = s * s;
        #pragma unroll
        for (int o = 32; o >= 1; o >>= 1) v += __shfl_xor(v, o, 64);
        if ((tid & 63) == 0) red[tid >> 6] = v;
        __syncthreads();
        if (tid == 0) {
            const float S2 = red[0] + red[1] + red[2] + red[3];
            atomicAdd(out, -LOSS_SCALE * (TINV / (KK - 1)) * (S2 - (float)KK));
        }
    } else {
        const int i = (blockIdx.x - 800) * 256 + tid;
        float s = 0.0f;
        if (i < BB * MM) {
            const int b = i / MM;
            const int r = i - b * MM;
            s = logf(denom_g[b * MP + r]);
        }
        #pragma unroll
        for (int o = 32; o >= 1; o >>= 1) s += __shfl_xor(s, o, 64);
        if ((tid & 63) == 0) red[tid >> 6] = s;
        __syncthreads();
        if (tid == 0)
            atomicAdd(out, (red[0] + red[1] + red[2] + red[3]) * LOSS_SCALE);
    }
}

extern "C" void kernel_launch(void* const* d_in, const int* in_sizes, int n_in,
                              void* d_out, int out_size, void* d_ws, size_t ws_size,
                              hipStream_t stream) {
    const float* x = (const float*)d_in[0];
    float* out = (float*)d_out;
    float* denom_g = (float*)d_ws;                 // 16384 floats
    float* invn = denom_g + BB * MP;               // 16384 floats
    ushort* xb = (ushort*)(invn + BB * MP);        // 8*2048*256 bf16 = 8 MB

    norm_bf16<<<BB * MP / 4, 256, 0, stream>>>(x, xb, invn, denom_g, out);
    cl_mfma<<<BB * 16 * 16, 256, 0, stream>>>(xb, denom_g);
    finalize_combined<<<800 + 63, 256, 0, stream>>>(x, invn, denom_g, out);
}

// Round 10
// 106.900 us; speedup vs baseline: 1.3151x; 1.3151x over previous
//
#include <hip/hip_runtime.h>
#include <math.h>

#define BB 8
#define NN 100
#define KK 20
#define DD 256
#define MM 2000                    // NN*KK anchors per batch
#define MP 2048                    // padded rows per batch
#define NPAD 48.0f                 // padded cols per row, each contributing exp(0)=1
#define TINV 10.0f                 // 1/TEMP
#define C2   14.4269504089f        // TINV * log2(e): exp(sim*TINV) = exp2(sim*C2)
#define LOSS_SCALE 1.953125e-7f    // ALPHA / (B_NORM*N*K*D) = 0.1/512000

typedef __bf16 bf16x8 __attribute__((ext_vector_type(8)));
typedef float floatx4 __attribute__((ext_vector_type(4)));
typedef __attribute__((address_space(1))) const ushort GUshort;
typedef __attribute__((address_space(3))) ushort LUshort;

__device__ __forceinline__ ushort f2bf(float f) {
    unsigned int u = __float_as_uint(f);
    u += 0x7fffu + ((u >> 16) & 1u);   // round-to-nearest-even
    return (ushort)(u >> 16);
}

// ---------------- kernel 1: normalize+convert to bf16, zero-pad, write invn, zero accumulators ----------------
__global__ void norm_bf16(const float* __restrict__ x, ushort* __restrict__ xb,
                          float* __restrict__ invn_out,
                          float* __restrict__ denom_g, float* __restrict__ out) {
    if (blockIdx.x < 16)
        ((float4*)denom_g)[blockIdx.x * 256 + threadIdx.x] = make_float4(0.f, 0.f, 0.f, 0.f);
    if (blockIdx.x == 0 && threadIdx.x == 0) out[0] = 0.0f;

    const int rg = blockIdx.x * 4 + (threadIdx.x >> 6);   // 0..16383
    const int lane = threadIdx.x & 63;
    const int b = rg >> 11;
    const int r = rg & (MP - 1);
    ushort4 outv = make_ushort4(0, 0, 0, 0);
    if (r < MM) {   // wave-uniform branch
        const float4 v = ((const float4*)(x + ((size_t)(b * MM + r)) * DD))[lane];
        float s = v.x * v.x + v.y * v.y + v.z * v.z + v.w * v.w;
        #pragma unroll
        for (int o = 32; o >= 1; o >>= 1) s += __shfl_xor(s, o, 64);
        const float inv = 1.0f / sqrtf(s);
        if (lane == 0) invn_out[rg] = inv;
        outv.x = f2bf(v.x * inv);
        outv.y = f2bf(v.y * inv);
        outv.z = f2bf(v.z * inv);
        outv.w = f2bf(v.w * inv);
    }
    ((ushort4*)(xb + (size_t)rg * DD))[lane] = outv;
}

// ---------------- kernel 2: FULL-GRID MFMA Gram + lean exp-sum epilogue ----------------
// 2048 blocks = 8 batches x 16x16 tile grid; DMA staging via global_load_lds(16B),
// granule-XOR swizzle (0 conflicts), XCD-pinned batch = blk&7. Epilogue leaned out:
// padded cols kept (exp(0)=1, subtracted analytically in finalize), diagonal handled
// only by the 256/8192 waves whose strips intersect, cross-lane reduction via LDS
// transpose (reuses staging LDS) instead of 64 bpermute chain steps per wave.
__global__ __launch_bounds__(256)
void cl_mfma(const ushort* __restrict__ xb, float* __restrict__ denom_g) {
    __shared__ __align__(16) ushort SMEM[2 * 128 * 64];   // As | Bs, 32 KB
    ushort* As = SMEM;
    ushort* Bs = SMEM + 128 * 64;

    const int b = blockIdx.x & 7;            // XCD pin
    const int ti = (blockIdx.x >> 3) & 15;   // row tile
    const int tj = blockIdx.x >> 7;          // col tile
    const int rbase = ti << 7;
    const int cbase = tj << 7;
    const ushort* __restrict__ xbb = xb + (size_t)b * MP * DD;

    const int tid = threadIdx.x;
    const int lane = tid & 63;
    const int w = tid >> 6;
    const int wr = (w >> 1) << 6;   // wave row offset within 128-tile
    const int wc = (w & 1) << 6;    // wave col offset
    const int tx = lane & 15;
    const int tx7 = tx & 7;
    const int quad = lane >> 4;
    // this wave's strips; diagonal only when they coincide (wave-uniform)
    const bool diagw = (rbase + wr) == (cbase + wc);

    // staging lane roles: 8 rows x 8 granule-slots per instruction
    const int srow = lane >> 3;
    const int sg = (lane & 7) ^ srow;

    floatx4 acc[4][4];
    #pragma unroll
    for (int mt = 0; mt < 4; ++mt)
        #pragma unroll
        for (int nt = 0; nt < 4; ++nt)
            acc[mt][nt] = (floatx4){0.f, 0.f, 0.f, 0.f};

    #pragma unroll 1
    for (int kc = 0; kc < 4; ++kc) {
        __syncthreads();
        #pragma unroll
        for (int q = 0; q < 4; ++q) {
            const int R = ((w << 2) + q) << 3;            // 8-row chunk base
            const size_t koff = (kc << 6) + (sg << 3);
            __builtin_amdgcn_global_load_lds(
                (GUshort*)(xbb + (size_t)(rbase + R + srow) * DD + koff),
                (LUshort*)(As + R * 64), 16, 0, 0);
            __builtin_amdgcn_global_load_lds(
                (GUshort*)(xbb + (size_t)(cbase + R + srow) * DD + koff),
                (LUshort*)(Bs + R * 64), 16, 0, 0);
        }
        __syncthreads();

        #pragma unroll
        for (int ks = 0; ks < 2; ++ks) {
            const int g = (ks << 2) + quad;          // logical granule
            const int gp = (g ^ tx7) << 3;           // swizzled ushort offset
            bf16x8 af[4], bf[4];
            #pragma unroll
            for (int mt = 0; mt < 4; ++mt)
                af[mt] = *(const bf16x8*)(As + (wr + (mt << 4) + tx) * 64 + gp);
            #pragma unroll
            for (int nt = 0; nt < 4; ++nt)
                bf[nt] = *(const bf16x8*)(Bs + (wc + (nt << 4) + tx) * 64 + gp);
            #pragma unroll
            for (int mt = 0; mt < 4; ++mt)
                #pragma unroll
                for (int nt = 0; nt < 4; ++nt)
                    acc[mt][nt] = __builtin_amdgcn_mfma_f32_16x16x32_bf16(af[mt], bf[nt], acc[mt][nt], 0, 0, 0);
        }
    }

    // ---- lean epilogue ----
    // Wait for all waves' last frag reads before overwriting LDS as scratch.
    __syncthreads();
    // per-wave scratch: 64 rows x stride 20 floats (5120 B per wave)
    float* P = (float*)SMEM + w * (64 * 20);

    #pragma unroll
    for (int mt = 0; mt < 4; ++mt) {
        #pragma unroll
        for (int i = 0; i < 4; ++i) {
            float de = 0.f;
            #pragma unroll
            for (int nt = 0; nt < 4; ++nt)
                de += exp2f(acc[mt][nt][i] * C2);
            if (diagw && tx == ((quad << 2) + i))
                de -= exp2f(acc[mt][mt][i] * C2);   // remove self term exactly
            P[((mt << 4) + (quad << 2) + i) * 20 + tx] = de;
        }
    }
    __syncthreads();   // ordering of per-wave LDS write->read (conservative)

    // lane j sums the 16 tx-partials of local row j, one coalesced atomic per lane
    const float4 p0 = *(const float4*)(P + lane * 20);
    const float4 p1 = *(const float4*)(P + lane * 20 + 4);
    const float4 p2 = *(const float4*)(P + lane * 20 + 8);
    const float4 p3 = *(const float4*)(P + lane * 20 + 12);
    const float sum = ((p0.x + p0.y) + (p0.z + p0.w)) + ((p1.x + p1.y) + (p1.z + p1.w))
                    + ((p2.x + p2.y) + (p2.z + p2.w)) + ((p3.x + p3.y) + (p3.z + p3.w));
    atomicAdd(&denom_g[b * MP + rbase + wr + lane], sum);
}

// ---------------- kernel 3: fused finalize ----------------
// blocks 0..799: class-group sum vectors -> analytic sum_term, atomicAdd into out
// blocks 800..862: log(denom - 48) partial sums, atomicAdd into out
__global__ void finalize_combined(const float* __restrict__ x,
                                  const float* __restrict__ invn,
                                  const float* __restrict__ denom_g,
                                  float* __restrict__ out) {
    __shared__ float red[4];
    const int tid = threadIdx.x;
    if (blockIdx.x < 800) {
        const int g = blockIdx.x;
        const int b = g / NN;
        const int n = g - b * NN;
        const int row0 = n * KK;
        const float* __restrict__ xg = x + ((size_t)(b * MM + row0)) * DD;
        const float* __restrict__ ig = invn + b * MP + row0;
        float s = 0.0f;
        #pragma unroll
        for (int k = 0; k < KK; ++k)
            s = fmaf(ig[k], xg[(size_t)k * DD + tid], s);
        float v = s * s;
        #pragma unroll
        for (int o = 32; o >= 1; o >>= 1) v += __shfl_xor(v, o, 64);
        if ((tid & 63) == 0) red[tid >> 6] = v;
        __syncthreads();
        if (tid == 0) {
            const float S2 = red[0] + red[1] + red[2] + red[3];
            atomicAdd(out, -LOSS_SCALE * (TINV / (KK - 1)) * (S2 - (float)KK));
        }
    } else {
        const int i = (blockIdx.x - 800) * 256 + tid;
        float s = 0.0f;
        if (i < BB * MM) {
            const int b = i / MM;
            const int r = i - b * MM;
            s = logf(denom_g[b * MP + r] - NPAD);   // remove the 48 padded-col exp(0) terms
        }
        #pragma unroll
        for (int o = 32; o >= 1; o >>= 1) s += __shfl_xor(s, o, 64);
        if ((tid & 63) == 0) red[tid >> 6] = s;
        __syncthreads();
        if (tid == 0)
            atomicAdd(out, (red[0] + red[1] + red[2] + red[3]) * LOSS_SCALE);
    }
}

extern "C" void kernel_launch(void* const* d_in, const int* in_sizes, int n_in,
                              void* d_out, int out_size, void* d_ws, size_t ws_size,
                              hipStream_t stream) {
    const float* x = (const float*)d_in[0];
    float* out = (float*)d_out;
    float* denom_g = (float*)d_ws;                 // 16384 floats
    float* invn = denom_g + BB * MP;               // 16384 floats
    ushort* xb = (ushort*)(invn + BB * MP);        // 8*2048*256 bf16 = 8 MB

    norm_bf16<<<BB * MP / 4, 256, 0, stream>>>(x, xb, invn, denom_g, out);
    cl_mfma<<<BB * 16 * 16, 256, 0, stream>>>(xb, denom_g);
    finalize_combined<<<800 + 63, 256, 0, stream>>>(x, invn, denom_g, out);
}